// Round 5
// baseline (178.490 us; speedup 1.0000x reference)
//
#include <hip/hip_runtime.h>
#include <hip/hip_bf16.h>

#define G_ 8
#define GIN_ 256
#define GOUT_ 256
#define NROWS_ 8192
#define LDX_ 2048   // = G_*GIN_ = row stride of x and out

typedef __attribute__((ext_vector_type(4))) float f32x4;
typedef __attribute__((ext_vector_type(8))) short bf16x8;

// ---------------------------------------------------------------------------
// Prep: W [G][GIN][GOUT] f32  ->  Wt [G][GOUT][GIN] bf16 (transposed+converted)
// Grid: 128 blocks x 256 threads. LDS-tiled transpose: coalesced both ways.
// ---------------------------------------------------------------------------
__global__ __launch_bounds__(256) void wprep_kernel(const float* __restrict__ W,
                                                    __hip_bfloat16* __restrict__ Wt) {
    __shared__ float tile[64][65];   // +1 pad: conflict-free transposed read
    const int bid = blockIdx.x;
    const int g  = bid >> 4;
    const int ot = (bid >> 2) & 3;   // o-tile (64 wide)
    const int it = bid & 3;          // i-tile (64 wide)
    const float* Wg = W + g * GIN_ * GOUT_;
    __hip_bfloat16* Wtg = Wt + g * GIN_ * GOUT_;
    const int lane_o = threadIdx.x & 63;
    const int sub    = threadIdx.x >> 6;   // 0..3
#pragma unroll
    for (int r = 0; r < 16; ++r) {
        int i = r * 4 + sub;
        tile[i][lane_o] = Wg[(it * 64 + i) * GOUT_ + ot * 64 + lane_o];
    }
    __syncthreads();
#pragma unroll
    for (int r = 0; r < 16; ++r) {
        int o = r * 4 + sub;
        Wtg[(ot * 64 + o) * GIN_ + it * 64 + lane_o] = __float2bfloat16(tile[lane_o][o]);
    }
}

// ---------------------------------------------------------------------------
// Main fused kernel — single-burst async DMA staging, LDS-only K-loop.
//  Block tile: 32M x 64N of one group. 4 waves in 2x2; wave = 16M x 32N
//  (acc = 2 MFMA tiles = 8 VGPRs).
//  Staging: ALL global loads are __builtin_amdgcn_global_load_lds (16B) —
//  no data VGPRs, so the register allocator CANNOT collapse the pipeline
//  (the R2/R3/R4 failure). 16 DMAs/thread in flight, then ONE barrier.
//   - A: x tile staged as f32 (32 KB), fragment-ordered [kk][wrow][h][lane],
//     f32->bf16 conversion happens in the K-loop (VALU has headroom).
//   - B: Wt strip bf16 (32 KB), fragment-ordered [kk][nt][lane].
//  Fragment order = DMA's lane*16B layout = conflict-free ds_read_b128.
//  64 KB LDS -> 2 blocks/CU: one block computes while the other drains DMA.
// Grid: 256 mtiles * 4 strips * 8 groups = 8192 blocks; bid%8 = g so each
// group's weights (128 KB) stay L2-resident on one XCD; the 4 strips sharing
// an x-slice are within a 32-bid window -> co-resident -> L2-local x reuse.
// ---------------------------------------------------------------------------
__global__ __launch_bounds__(256) void gkan_kernel(const float* __restrict__ x,
                                                   const __hip_bfloat16* __restrict__ Wt,
                                                   const float* __restrict__ bias,
                                                   const float* __restrict__ pc,
                                                   const float* __restrict__ qc,
                                                   float* __restrict__ out) {
    __shared__ __align__(16) float          As[8 * 2 * 2 * 64 * 4];   // 32 KB
    __shared__ __align__(16) __hip_bfloat16 Bsh[8 * 4 * 64 * 8];      // 32 KB

    const int bid   = blockIdx.x;
    const int g     = bid & 7;
    const int rest  = bid >> 3;
    const int strip = rest & 3;          // 64-col strip within group
    const int mtile = rest >> 2;         // 0..255 : 32-row tiles
    const int n0    = strip * 64;
    const int m0    = mtile * 32;

    const int t    = threadIdx.x;
    const int wave = t >> 6;
    const int lane = t & 63;
    const int lm   = lane & 15;
    const int quad = lane >> 4;
    const int wrow = wave >> 1;          // m-half (0,1)
    const int wcol = wave & 1;           // n-half (0,1)

    // ---- single DMA burst: 16 x global_load_lds (16B) per thread ----
    // A: 32 wave-instrs total = (kk 8) x (wr 2) x (h 2); wave w does kk=2w,2w+1
    const float* xg = x + (size_t)(m0 + lm) * LDX_ + g * GIN_ + quad * 8;
#pragma unroll
    for (int s = 0; s < 2; ++s) {
        const int kk = wave * 2 + s;
#pragma unroll
        for (int wr = 0; wr < 2; ++wr) {
#pragma unroll
            for (int h = 0; h < 2; ++h) {
                const float* src = xg + (size_t)wr * 16 * LDX_ + kk * 32 + h * 4;
                float* dst = &As[(((kk * 2 + wr) * 2 + h) * 64) * 4];
                __builtin_amdgcn_global_load_lds(
                    (const __attribute__((address_space(1))) unsigned int*)src,
                    (__attribute__((address_space(3))) unsigned int*)dst, 16, 0, 0);
            }
        }
    }
    // B: 32 wave-instrs total = (kk 8) x (nt 4); wave w does kk=2w,2w+1
    const __hip_bfloat16* wg = Wt + (size_t)g * (GIN_ * GOUT_)
                                  + (size_t)(n0 + lm) * GIN_ + quad * 8;
#pragma unroll
    for (int s = 0; s < 2; ++s) {
        const int kk = wave * 2 + s;
#pragma unroll
        for (int nt = 0; nt < 4; ++nt) {
            const __hip_bfloat16* src = wg + (size_t)nt * 16 * GIN_ + kk * 32;
            __hip_bfloat16* dst = &Bsh[((kk * 4 + nt) * 64) * 8];
            __builtin_amdgcn_global_load_lds(
                (const __attribute__((address_space(1))) unsigned int*)src,
                (__attribute__((address_space(3))) unsigned int*)dst, 16, 0, 0);
        }
    }
    __syncthreads();   // the only barrier

    // ---- LDS-only K-loop ----
    f32x4 acc[2] = {};
#pragma unroll
    for (int kk = 0; kk < 8; ++kk) {
        const f32x4 a0 = *(const f32x4*)&As[(((kk * 2 + wrow) * 2 + 0) * 64 + lane) * 4];
        const f32x4 a1 = *(const f32x4*)&As[(((kk * 2 + wrow) * 2 + 1) * 64 + lane) * 4];
        const bf16x8 b0 = *(const bf16x8*)&Bsh[((kk * 4 + wcol * 2 + 0) * 64 + lane) * 8];
        const bf16x8 b1 = *(const bf16x8*)&Bsh[((kk * 4 + wcol * 2 + 1) * 64 + lane) * 8];
        union { __hip_bfloat16 h[8]; bf16x8 v; } cv;
        cv.h[0] = __float2bfloat16(a0.x);
        cv.h[1] = __float2bfloat16(a0.y);
        cv.h[2] = __float2bfloat16(a0.z);
        cv.h[3] = __float2bfloat16(a0.w);
        cv.h[4] = __float2bfloat16(a1.x);
        cv.h[5] = __float2bfloat16(a1.y);
        cv.h[6] = __float2bfloat16(a1.z);
        cv.h[7] = __float2bfloat16(a1.w);
        acc[0] = __builtin_amdgcn_mfma_f32_16x16x32_bf16(cv.v, b0, acc[0], 0, 0, 0);
        acc[1] = __builtin_amdgcn_mfma_f32_16x16x32_bf16(cv.v, b1, acc[1], 0, 0, 0);
    }

    // ---- epilogue: bias + rational, coalesced dword stores ----
    const float p0 = pc[g * 4 + 0], p1 = pc[g * 4 + 1];
    const float p2 = pc[g * 4 + 2], p3 = pc[g * 4 + 3];
    const float q0 = qc[g * 3 + 0], q1 = qc[g * 3 + 1], q2 = qc[g * 3 + 2];

#pragma unroll
    for (int sub = 0; sub < 2; ++sub) {
        const int col = n0 + wcol * 32 + sub * 16 + lm;   // within group
        const float bb = bias[g * GOUT_ + col];
#pragma unroll
        for (int r = 0; r < 4; ++r) {
            const int row = m0 + wrow * 16 + quad * 4 + r;
            const float y   = acc[sub][r] + bb;
            const float num = p0 + y * (p1 + y * (p2 + y * p3));
            const float den = 1.0f + fabsf(y * (q0 + y * (q1 + y * q2)));
            out[(size_t)row * LDX_ + g * GOUT_ + col] = num * __builtin_amdgcn_rcpf(den);
        }
    }
}

extern "C" void kernel_launch(void* const* d_in, const int* in_sizes, int n_in,
                              void* d_out, int out_size, void* d_ws, size_t ws_size,
                              hipStream_t stream) {
    const float* x = (const float*)d_in[0];
    const float* W = (const float*)d_in[1];
    const float* b = (const float*)d_in[2];
    const float* p = (const float*)d_in[3];
    const float* q = (const float*)d_in[4];
    float* out = (float*)d_out;

    __hip_bfloat16* Wt = (__hip_bfloat16*)d_ws;   // 1 MiB bf16 transposed W

    wprep_kernel<<<128, 256, 0, stream>>>(W, Wt);
    gkan_kernel<<<8192, 256, 0, stream>>>(x, Wt, b, p, q, out);
}

// Round 6
// 136.423 us; speedup vs baseline: 1.3084x; 1.3084x over previous
//
#include <hip/hip_runtime.h>
#include <hip/hip_bf16.h>

#define G_ 8
#define GIN_ 256
#define GOUT_ 256
#define NROWS_ 8192
#define LDX_ 2048   // = G_*GIN_ = row stride of x and out

typedef __attribute__((ext_vector_type(4))) float f32x4;
typedef __attribute__((ext_vector_type(8))) short bf16x8;

// ---------------------------------------------------------------------------
// Prep: W [G][GIN][GOUT] f32  ->  Wt [G][GOUT][GIN] bf16 (transposed+converted)
// Grid: 128 blocks x 256 threads. LDS-tiled transpose: coalesced both ways.
// ---------------------------------------------------------------------------
__global__ __launch_bounds__(256) void wprep_kernel(const float* __restrict__ W,
                                                    __hip_bfloat16* __restrict__ Wt) {
    __shared__ float tile[64][65];   // +1 pad: conflict-free transposed read
    const int bid = blockIdx.x;
    const int g  = bid >> 4;
    const int ot = (bid >> 2) & 3;   // o-tile (64 wide)
    const int it = bid & 3;          // i-tile (64 wide)
    const float* Wg = W + g * GIN_ * GOUT_;
    __hip_bfloat16* Wtg = Wt + g * GIN_ * GOUT_;
    const int lane_o = threadIdx.x & 63;
    const int sub    = threadIdx.x >> 6;   // 0..3
#pragma unroll
    for (int r = 0; r < 16; ++r) {
        int i = r * 4 + sub;
        tile[i][lane_o] = Wg[(it * 64 + i) * GOUT_ + ot * 64 + lane_o];
    }
    __syncthreads();
#pragma unroll
    for (int r = 0; r < 16; ++r) {
        int o = r * 4 + sub;
        Wtg[(ot * 64 + o) * GIN_ + it * 64 + lane_o] = __float2bfloat16(tile[lane_o][o]);
    }
}

// ---------------------------------------------------------------------------
// Main fused kernel — traffic-minimal: x is read from global EXACTLY ONCE.
//  Block = 512 threads (8 waves), covers the FULL 256-col width of one group
//  for a 128-row range (4 slabs of 32 rows).
//  - B: per-wave 32 cols x full K=256 in REGISTERS (64 VGPRs; used every
//    chunk so the allocator can neither collapse nor profitably spill it).
//  - A: 32-row x-slab staged f32->bf16 into LDS (16 KB), double-buffered,
//    BROADCAST to all 8 waves — this removes the 2-4x x re-read that made
//    R1-R5 traffic-bound at the ~6 TB/s aggregate LLC/HBM ceiling.
//  - LDS layout: row stride 512 B, 16B-granule XOR swizzle (gh ^ (row&7))
//    -> uniform 8 lanes/bank-group for both ds_write_b128 and ds_read_b128.
//  - One barrier per slab; next slab's global loads (16 VGPRs) are issued
//    BEFORE the MFMA loop so compute covers their latency.
// Grid: 8 groups x 64 row-blocks = 512 blocks; bid&7 = g -> W[g] L2-local.
// ---------------------------------------------------------------------------
__global__ __launch_bounds__(512, 4) void gkan_kernel(const float* __restrict__ x,
                                                      const __hip_bfloat16* __restrict__ Wt,
                                                      const float* __restrict__ bias,
                                                      const float* __restrict__ pc,
                                                      const float* __restrict__ qc,
                                                      float* __restrict__ out) {
    __shared__ __align__(16) __hip_bfloat16 As[2][32 * 256];   // 2 x 16 KB

    const int bid    = blockIdx.x;
    const int g      = bid & 7;
    const int mblock = bid >> 3;        // 0..63
    const int row0   = mblock * 128;

    const int t    = threadIdx.x;
    const int wave = t >> 6;            // 0..7 -> cols [wave*32, +32)
    const int lane = t & 63;
    const int lm   = lane & 15;
    const int quad = lane >> 4;

    // ---- B: register-resident, wave's 32 cols x K=256 (64 VGPRs) ----
    bf16x8 Breg[2][8];
    {
        const __hip_bfloat16* Wg = Wt + (size_t)g * (GIN_ * GOUT_)
                                      + (size_t)(wave * 32) * GIN_;
#pragma unroll
        for (int nt = 0; nt < 2; ++nt)
#pragma unroll
            for (int c = 0; c < 8; ++c)
                Breg[nt][c] = *(const bf16x8*)(Wg + (size_t)(nt * 16 + lm) * GIN_
                                                  + c * 32 + quad * 8);
    }

    // ---- per-lane constants (hoisted out of the slab loop) ----
    const float p0 = pc[g * 4 + 0], p1 = pc[g * 4 + 1];
    const float p2 = pc[g * 4 + 2], p3 = pc[g * 4 + 3];
    const float q0 = qc[g * 3 + 0], q1 = qc[g * 3 + 1], q2 = qc[g * 3 + 2];
    float bb[2];
#pragma unroll
    for (int nt = 0; nt < 2; ++nt)
        bb[nt] = bias[g * GOUT_ + wave * 32 + nt * 16 + lm];

    // ---- staging geometry: thread owns 16 f32 of one slab row ----
    const int sr = t >> 4;              // 0..31  slab row
    const int su = t & 15;              // 0..15  32B unit within row
    const float* xs = x + (size_t)(row0 + sr) * LDX_ + g * GIN_ + su * 16;
    const int go0 = (((2 * su)     ^ (sr & 7)) * 8);   // swizzled bf16 offsets
    const int go1 = (((2 * su + 1) ^ (sr & 7)) * 8);
    __hip_bfloat16* row_b0 = &As[0][sr * 256];
    __hip_bfloat16* row_b1 = &As[1][sr * 256];

    f32x4 st0, st1, st2, st3;
    st0 = *(const f32x4*)(xs);
    st1 = *(const f32x4*)(xs + 4);
    st2 = *(const f32x4*)(xs + 8);
    st3 = *(const f32x4*)(xs + 12);
    {
        union { __hip_bfloat16 h[8]; bf16x8 v; } ca, cb;
        ca.h[0] = __float2bfloat16(st0.x); ca.h[1] = __float2bfloat16(st0.y);
        ca.h[2] = __float2bfloat16(st0.z); ca.h[3] = __float2bfloat16(st0.w);
        ca.h[4] = __float2bfloat16(st1.x); ca.h[5] = __float2bfloat16(st1.y);
        ca.h[6] = __float2bfloat16(st1.z); ca.h[7] = __float2bfloat16(st1.w);
        cb.h[0] = __float2bfloat16(st2.x); cb.h[1] = __float2bfloat16(st2.y);
        cb.h[2] = __float2bfloat16(st2.z); cb.h[3] = __float2bfloat16(st2.w);
        cb.h[4] = __float2bfloat16(st3.x); cb.h[5] = __float2bfloat16(st3.y);
        cb.h[6] = __float2bfloat16(st3.z); cb.h[7] = __float2bfloat16(st3.w);
        *(bf16x8*)(row_b0 + go0) = ca.v;
        *(bf16x8*)(row_b0 + go1) = cb.v;
    }
    __syncthreads();

#pragma unroll 1
    for (int s = 0; s < 4; ++s) {
        // prefetch next slab's x (issued before compute; vmcnt hidden by MFMA)
        if (s < 3) {
            const float* xn = xs + (size_t)(s + 1) * 32 * LDX_;
            st0 = *(const f32x4*)(xn);
            st1 = *(const f32x4*)(xn + 4);
            st2 = *(const f32x4*)(xn + 8);
            st3 = *(const f32x4*)(xn + 12);
        }

        // ---- compute slab s ----
        const __hip_bfloat16* slab = As[s & 1];
        f32x4 acc[2][2] = {};
#pragma unroll
        for (int c = 0; c < 8; ++c) {
            bf16x8 af[2];
#pragma unroll
            for (int mt = 0; mt < 2; ++mt) {
                const int gh = (c * 4 + quad) ^ (lm & 7);
                af[mt] = *(const bf16x8*)(slab + (mt * 16 + lm) * 256 + gh * 8);
            }
#pragma unroll
            for (int mt = 0; mt < 2; ++mt)
#pragma unroll
                for (int nt = 0; nt < 2; ++nt)
                    acc[mt][nt] = __builtin_amdgcn_mfma_f32_16x16x32_bf16(
                        af[mt], Breg[nt][c], acc[mt][nt], 0, 0, 0);
        }

        // ---- epilogue for slab s: bias + rational, coalesced stores ----
#pragma unroll
        for (int nt = 0; nt < 2; ++nt) {
            const int col = g * GOUT_ + wave * 32 + nt * 16 + lm;
#pragma unroll
            for (int mt = 0; mt < 2; ++mt)
#pragma unroll
                for (int r = 0; r < 4; ++r) {
                    const int row = row0 + s * 32 + mt * 16 + quad * 4 + r;
                    const float y   = acc[mt][nt][r] + bb[nt];
                    const float num = p0 + y * (p1 + y * (p2 + y * p3));
                    const float den = 1.0f + fabsf(y * (q0 + y * (q1 + y * q2)));
                    out[(size_t)row * LDX_ + col] = num * __builtin_amdgcn_rcpf(den);
                }
        }

        // ---- convert + write next slab into the other buffer ----
        if (s < 3) {
            __hip_bfloat16* dst = (s & 1) ? row_b0 : row_b1;
            union { __hip_bfloat16 h[8]; bf16x8 v; } ca, cb;
            ca.h[0] = __float2bfloat16(st0.x); ca.h[1] = __float2bfloat16(st0.y);
            ca.h[2] = __float2bfloat16(st0.z); ca.h[3] = __float2bfloat16(st0.w);
            ca.h[4] = __float2bfloat16(st1.x); ca.h[5] = __float2bfloat16(st1.y);
            ca.h[6] = __float2bfloat16(st1.z); ca.h[7] = __float2bfloat16(st1.w);
            cb.h[0] = __float2bfloat16(st2.x); cb.h[1] = __float2bfloat16(st2.y);
            cb.h[2] = __float2bfloat16(st2.z); cb.h[3] = __float2bfloat16(st2.w);
            cb.h[4] = __float2bfloat16(st3.x); cb.h[5] = __float2bfloat16(st3.y);
            cb.h[6] = __float2bfloat16(st3.z); cb.h[7] = __float2bfloat16(st3.w);
            *(bf16x8*)(dst + go0) = ca.v;
            *(bf16x8*)(dst + go1) = cb.v;
            __syncthreads();
        }
    }
}

extern "C" void kernel_launch(void* const* d_in, const int* in_sizes, int n_in,
                              void* d_out, int out_size, void* d_ws, size_t ws_size,
                              hipStream_t stream) {
    const float* x = (const float*)d_in[0];
    const float* W = (const float*)d_in[1];
    const float* b = (const float*)d_in[2];
    const float* p = (const float*)d_in[3];
    const float* q = (const float*)d_in[4];
    float* out = (float*)d_out;

    __hip_bfloat16* Wt = (__hip_bfloat16*)d_ws;   // 1 MiB bf16 transposed W

    wprep_kernel<<<128, 256, 0, stream>>>(W, Wt);
    gkan_kernel<<<512, 512, 0, stream>>>(x, Wt, b, p, q, out);
}